// Round 5
// baseline (290.164 us; speedup 1.0000x reference)
//
#include <hip/hip_runtime.h>

typedef float  f32x4 __attribute__((ext_vector_type(4)));
typedef short  s16x8 __attribute__((ext_vector_type(8)));
typedef unsigned short u16x8 __attribute__((ext_vector_type(8)));

#define NROWS 4096
#define FOUT  256
#define ALPHA_LR 0.2f
#define SCALE 0.0625f
#define NEGV  -9.0e15f

static __device__ __forceinline__ unsigned short bf16_rne(float x) {
    unsigned u = __float_as_uint(x);
    u += 0x7fffu + ((u >> 16) & 1u);
    return (unsigned short)(u >> 16);
}
static __device__ __forceinline__ unsigned short bf16_trunc(float x) {
    return (unsigned short)(__float_as_uint(x) >> 16);
}
static __device__ __forceinline__ float bf2f(unsigned short h) {
    return __uint_as_float(((unsigned)h) << 16);
}
static __device__ __forceinline__ float wmax16(float v) {
#pragma unroll
    for (int o = 8; o; o >>= 1) v = fmaxf(v, __shfl_xor(v, o, 16));
    return v;
}
static __device__ __forceinline__ float wsum16(float v) {
#pragma unroll
    for (int o = 8; o; o >>= 1) v += __shfl_xor(v, o, 16);
    return v;
}
static __device__ __forceinline__ float wmax32(float v) {
#pragma unroll
    for (int o = 16; o; o >>= 1) v = fmaxf(v, __shfl_xor(v, o, 32));
    return v;
}
static __device__ __forceinline__ float wsum32(float v) {
#pragma unroll
    for (int o = 16; o; o >>= 1) v += __shfl_xor(v, o, 32);
    return v;
}

// ---------------------------------------------------------------------------
// Convert W (512x256) and Wqkv_w (768x256) to bf16 hi/lo.
// ---------------------------------------------------------------------------
__global__ __launch_bounds__(256) void wprep(
    const float* __restrict__ W, const float* __restrict__ Wq,
    unsigned short* __restrict__ Whi, unsigned short* __restrict__ Wlo,
    unsigned short* __restrict__ Qhi, unsigned short* __restrict__ Qlo)
{
    int i = blockIdx.x * 256 + threadIdx.x;
    if (i < 131072) {
        float v = W[i];
        unsigned short hh = bf16_trunc(v);
        Whi[i] = hh; Wlo[i] = bf16_rne(v - bf2f(hh));
    }
    if (i < 196608) {
        float v = Wq[i];
        unsigned short hh = bf16_trunc(v);
        Qhi[i] = hh; Qlo[i] = bf16_rne(v - bf2f(hh));
    }
}

// ---------------------------------------------------------------------------
// MFMA GEMM, 3-term bf16 hi/lo split (error ~2^-14 rel).
// A fp32 [M][K] (converted inline). B pre-converted bf16 hi/lo [Nn][K].
// BM=BN=64, BK=32, 256 thr = 4 waves; wave w: rows w*16..+15 x 64 cols.
// EPI 1: C=f32 [M][Nn] AND o0[col*4096+row]=bf16   (Wh + WhT)
// EPI 2: col<256 -> o0[row][col] (q); <512 -> o1[row][col-256] (k);
//        else o2[(col-512)*4096+row] (vT)
// EPI 3: o0/o1 = hi/lo bf16 at [row*Nn+col]        (WcT)
// ---------------------------------------------------------------------------
template <int EPI, bool BIAS>
__global__ __launch_bounds__(256) void gemm_mfma(
    const float* __restrict__ A,
    const unsigned short* __restrict__ Bhi, const unsigned short* __restrict__ Blo,
    const float* __restrict__ bias,
    float* __restrict__ C, unsigned short* __restrict__ o0,
    unsigned short* __restrict__ o1, unsigned short* __restrict__ o2,
    int M, int Nn, int K)
{
    __shared__ unsigned short Ah[64][40];
    __shared__ unsigned short Al[64][40];
    __shared__ unsigned short Bh[64][40];
    __shared__ unsigned short Bl[64][40];

    const int tid = threadIdx.x;
    const int w = tid >> 6;
    const int ln = tid & 63;
    const int l15 = ln & 15;
    const int lhi = ln >> 4;
    const int bm = blockIdx.y * 64;
    const int bn = blockIdx.x * 64;
    const int sm = tid >> 2;
    const int sk = (tid & 3) * 8;

    f32x4 acc[4];
#pragma unroll
    for (int cf = 0; cf < 4; ++cf) acc[cf] = (f32x4){0.f, 0.f, 0.f, 0.f};

    const float* arow = &A[(size_t)(bm + sm) * K];
    const unsigned short* bhrow = &Bhi[(size_t)(bn + sm) * K];
    const unsigned short* blrow = &Blo[(size_t)(bn + sm) * K];

    float4 a0r = *(const float4*)(arow + sk);
    float4 a1r = *(const float4*)(arow + sk + 4);
    uint4 bhr = *(const uint4*)(bhrow + sk);
    uint4 blr = *(const uint4*)(blrow + sk);

    for (int k0 = 0; k0 < K; k0 += 32) {
        // convert A regs to hi/lo packed
        float vv[8] = {a0r.x, a0r.y, a0r.z, a0r.w, a1r.x, a1r.y, a1r.z, a1r.w};
        unsigned hp[4], lp[4];
#pragma unroll
        for (int q = 0; q < 4; ++q) {
            unsigned short h0 = bf16_trunc(vv[q * 2]);
            unsigned short h1 = bf16_trunc(vv[q * 2 + 1]);
            unsigned short l0 = bf16_rne(vv[q * 2] - bf2f(h0));
            unsigned short l1 = bf16_rne(vv[q * 2 + 1] - bf2f(h1));
            hp[q] = (unsigned)h0 | ((unsigned)h1 << 16);
            lp[q] = (unsigned)l0 | ((unsigned)l1 << 16);
        }
        __syncthreads();
        *(uint4*)&Ah[sm][sk] = make_uint4(hp[0], hp[1], hp[2], hp[3]);
        *(uint4*)&Al[sm][sk] = make_uint4(lp[0], lp[1], lp[2], lp[3]);
        *(uint4*)&Bh[sm][sk] = bhr;
        *(uint4*)&Bl[sm][sk] = blr;
        // issue next-tile loads
        const int kn = (k0 + 32 < K) ? k0 + 32 : 0;
        a0r = *(const float4*)(arow + kn + sk);
        a1r = *(const float4*)(arow + kn + sk + 4);
        bhr = *(const uint4*)(bhrow + kn + sk);
        blr = *(const uint4*)(blrow + kn + sk);
        __syncthreads();
        s16x8 ah = *(const s16x8*)&Ah[w * 16 + l15][lhi * 8];
        s16x8 al2 = *(const s16x8*)&Al[w * 16 + l15][lhi * 8];
        __builtin_amdgcn_s_setprio(1);
#pragma unroll
        for (int cf = 0; cf < 4; ++cf) {
            s16x8 bh = *(const s16x8*)&Bh[cf * 16 + l15][lhi * 8];
            s16x8 bl = *(const s16x8*)&Bl[cf * 16 + l15][lhi * 8];
            acc[cf] = __builtin_amdgcn_mfma_f32_16x16x32_bf16(ah, bh, acc[cf], 0, 0, 0);
            acc[cf] = __builtin_amdgcn_mfma_f32_16x16x32_bf16(ah, bl, acc[cf], 0, 0, 0);
            acc[cf] = __builtin_amdgcn_mfma_f32_16x16x32_bf16(al2, bh, acc[cf], 0, 0, 0);
        }
        __builtin_amdgcn_s_setprio(0);
    }

#pragma unroll
    for (int cf = 0; cf < 4; ++cf) {
        const int col = bn + cf * 16 + l15;
        float bv = BIAS ? bias[col] : 0.0f;
#pragma unroll
        for (int r = 0; r < 4; ++r) {
            const int row = bm + w * 16 + lhi * 4 + r;
            float v = acc[cf][r] + bv;
            if (EPI == 1) {
                C[(size_t)row * Nn + col] = v;
                o0[(size_t)col * NROWS + row] = bf16_rne(v);
            } else if (EPI == 2) {
                if (col < 256)      o0[(size_t)row * 256 + col] = bf16_rne(v);
                else if (col < 512) o1[(size_t)row * 256 + (col - 256)] = bf16_rne(v);
                else                o2[(size_t)(col - 512) * NROWS + row] = bf16_rne(v);
            } else {  // EPI 3
                unsigned short hh = bf16_trunc(v);
                o0[(size_t)row * Nn + col] = hh;
                o1[(size_t)row * Nn + col] = bf16_rne(v - bf2f(hh));
            }
        }
    }
}

// ---------------------------------------------------------------------------
// p1 = Wh @ a[:256], p2 = Wh @ a[256:]
// ---------------------------------------------------------------------------
__global__ __launch_bounds__(256) void compute_p(
    const float* __restrict__ Wh, const float* __restrict__ a,
    float* __restrict__ p1, float* __restrict__ p2)
{
    const int row = blockIdx.x * 16 + (threadIdx.x >> 4);
    const int c = threadIdx.x & 15;
    float s1 = 0.f, s2 = 0.f;
    for (int f = c; f < FOUT; f += 16) {
        float w = Wh[(size_t)row * FOUT + f];
        s1 += w * a[f];
        s2 += w * a[FOUT + f];
    }
    s1 = wsum16(s1);
    s2 = wsum16(s2);
    if (c == 0) { p1[row] = s1; p2[row] = s2; }
}

// ---------------------------------------------------------------------------
// Inner-attention stats, j-parallel. grid = 256 rowtiles x 8 chunks.
// ---------------------------------------------------------------------------
__global__ __launch_bounds__(256) void stats_kernel(
    const unsigned short* __restrict__ qh_g, const unsigned short* __restrict__ kh_g,
    float* __restrict__ stats)
{
    const int tid = threadIdx.x;
    const int h = tid >> 6;
    const int ln = tid & 63;
    const int l15 = ln & 15;
    const int lhi = ln >> 4;
    const int rt = blockIdx.x >> 3;
    const int ch = blockIdx.x & 7;
    const int i0 = rt * 16;

    s16x8 qA[2];
#pragma unroll
    for (int ks = 0; ks < 2; ++ks)
        qA[ks] = *(const s16x8*)(qh_g + (size_t)(i0 + l15) * 256 + h * 64 + ks * 32 + lhi * 8);

    float m[4], z[4];
#pragma unroll
    for (int r = 0; r < 4; ++r) { m[r] = -3.0e38f; z[r] = 0.f; }

    for (int tt = 0; tt < 16; ++tt) {
        const int j0 = ch * 512 + tt * 32;
        f32x4 acc[2] = {{0.f,0.f,0.f,0.f},{0.f,0.f,0.f,0.f}};
#pragma unroll
        for (int ks = 0; ks < 2; ++ks)
#pragma unroll
            for (int nt = 0; nt < 2; ++nt) {
                s16x8 kB = *(const s16x8*)(kh_g + (size_t)(j0 + nt * 16 + l15) * 256 +
                                           h * 64 + ks * 32 + lhi * 8);
                acc[nt] = __builtin_amdgcn_mfma_f32_16x16x32_bf16(qA[ks], kB, acc[nt], 0, 0, 0);
            }
#pragma unroll
        for (int r = 0; r < 4; ++r) {
            float s0 = acc[0][r] * SCALE, s1 = acc[1][r] * SCALE;
            float mn = fmaxf(m[r], fmaxf(s0, s1));
            z[r] = z[r] * __expf(m[r] - mn) + __expf(s0 - mn) + __expf(s1 - mn);
            m[r] = mn;
        }
    }
#pragma unroll
    for (int r = 0; r < 4; ++r) {
        float mm = m[r], zz = z[r];
#pragma unroll
        for (int o = 1; o < 16; o <<= 1) {
            float mo = __shfl_xor(mm, o, 16);
            float zo = __shfl_xor(zz, o, 16);
            float mn = fmaxf(mm, mo);
            zz = zz * __expf(mm - mn) + zo * __expf(mo - mn);
            mm = mn;
        }
        if (l15 == 0) {
            size_t idx = (((size_t)(i0 + lhi * 4 + r) * 4 + h) * 8 + ch) * 2;
            stats[idx] = mm;
            stats[idx + 1] = zz;
        }
    }
}

// ---------------------------------------------------------------------------
// Main fused sweep v2: direct-from-global MFMA fragments (no K/V/Wh LDS
// staging — per-wave slices are disjoint, so traffic is identical), 2
// barriers/tile, 1-tile register prefetch. grid = 256 rowtiles x 2 chunks.
// 512 thr = 8 waves = (head h 0..3) x (j-half jg 0..1). 64 tiles of 32 j.
// LDS: dots 4x16x80B, ptil 16x80B, alpha, merged stats -> ~7KB.
// ---------------------------------------------------------------------------
__global__ __launch_bounds__(512, 4) void main_attn(
    const unsigned short* __restrict__ qh_g, const unsigned short* __restrict__ kh_g,
    const unsigned short* __restrict__ vth_g, const unsigned short* __restrict__ wht_g,
    const float* __restrict__ stats, const float* __restrict__ p1g,
    const float* __restrict__ p2g, const int* __restrict__ adj,
    unsigned short* __restrict__ pacc_o, unsigned short* __restrict__ wacc_o,
    float* __restrict__ ml_o)
{
    enum { DOTS = 0, PTIL = 5120, ALP = 6400, MIZ = 6464, SMEMSZ = 6976 };
    __shared__ __align__(16) char smem[SMEMSZ];

    const int tid = threadIdx.x;
    const int w = tid >> 6;
    const int h = w & 3;
    const int jg = w >> 2;
    const int ln = tid & 63;
    const int l15 = ln & 15;
    const int lhi = ln >> 4;
    const int rt = blockIdx.x >> 1;
    const int ch = blockIdx.x & 1;
    const int i0 = rt * 16;
    const int jbase = ch * 2048;
    const int srow = tid >> 5;      // 0..15
    const int scol = tid & 31;      // 0..31

    // ---- merge inner-stats partials ----
    if (tid < 64) {
        int hh = tid >> 4, row = tid & 15;
        const float* sb = stats + ((size_t)(i0 + row) * 4 + hh) * 16;
        float M = -3.0e38f, Z = 0.f;
#pragma unroll
        for (int c = 0; c < 8; ++c) {
            float mc = sb[c * 2], zc = sb[c * 2 + 1];
            float mn = fmaxf(M, mc);
            Z = Z * __expf(M - mn) + zc * __expf(mc - mn);
            M = mn;
        }
        ((float*)(smem + MIZ))[(hh * 16 + row) * 2] = M;
        ((float*)(smem + MIZ))[(hh * 16 + row) * 2 + 1] = 1.0f / Z;
    }

    // persistent q fragments
    s16x8 qA[2];
#pragma unroll
    for (int ks = 0; ks < 2; ++ks)
        qA[ks] = *(const s16x8*)(qh_g + (size_t)(i0 + l15) * 256 + h * 64 + ks * 32 + lhi * 8);

    __syncthreads();

    float m_f[4], iz_f[4];
#pragma unroll
    for (int r = 0; r < 4; ++r) {
        m_f[r]  = ((float*)(smem + MIZ))[(h * 16 + lhi * 4 + r) * 2];
        iz_f[r] = ((float*)(smem + MIZ))[(h * 16 + lhi * 4 + r) * 2 + 1];
    }

    // per-lane global fragment base pointers
    const unsigned short* kp = kh_g + (size_t)(jg * 16 + l15) * 256 + h * 64 + lhi * 8;
    const unsigned short* vp = vth_g + (size_t)(h * 64 + jg * 32 + l15) * 4096 + lhi * 8;
    const unsigned short* wp = wht_g + (size_t)(h * 64 + jg * 32 + l15) * 4096 + lhi * 8;

    // prefetch tile 0
    s16x8 kf0 = *(const s16x8*)(kp + (size_t)jbase * 256);
    s16x8 kf1 = *(const s16x8*)(kp + (size_t)jbase * 256 + 32);
    s16x8 vf0 = *(const s16x8*)(vp + jbase);
    s16x8 vf1 = *(const s16x8*)(vp + 16 * 4096 + jbase);
    s16x8 wf0 = *(const s16x8*)(wp + jbase);
    s16x8 wf1 = *(const s16x8*)(wp + 16 * 4096 + jbase);
    int   adjc = adj[(size_t)(i0 + srow) * NROWS + jbase + scol];
    float p2c  = p2g[jbase + scol];

    f32x4 pacc[2] = {{0.f,0.f,0.f,0.f},{0.f,0.f,0.f,0.f}};
    f32x4 wacc[2] = {{0.f,0.f,0.f,0.f},{0.f,0.f,0.f,0.f}};
    float Mrun = -3.0e38f, Lrun = 0.0f;
    const float p1v = p1g[i0 + srow];

    const int dwbase = DOTS + h * 1280 + (jg * 16 + l15) * 2;
    const int daddr  = DOTS + h * 1280 + l15 * 80 + lhi * 16;
    const int paddr  = PTIL + l15 * 80 + lhi * 16;

    for (int t = 0; t < 64; ++t) {
        const int jn = jbase + ((t + 1) & 63) * 32;

        // ---- QK ----
        f32x4 qk = {0.f, 0.f, 0.f, 0.f};
        __builtin_amdgcn_s_setprio(1);
        qk = __builtin_amdgcn_mfma_f32_16x16x32_bf16(qA[0], kf0, qk, 0, 0, 0);
        qk = __builtin_amdgcn_mfma_f32_16x16x32_bf16(qA[1], kf1, qk, 0, 0, 0);
        __builtin_amdgcn_s_setprio(0);
        // prefetch K(t+1)
        kf0 = *(const s16x8*)(kp + (size_t)jn * 256);
        kf1 = *(const s16x8*)(kp + (size_t)jn * 256 + 32);
        // dots -> LDS bf16
#pragma unroll
        for (int r = 0; r < 4; ++r) {
            float d = __expf(qk[r] * SCALE - m_f[r]) * iz_f[r];
            *(unsigned short*)(smem + dwbase + (lhi * 4 + r) * 80) = bf16_rne(d);
        }
        __syncthreads();  // B1: dots visible

        // ---- PV ----
        {
            s16x8 dA = *(const s16x8*)(smem + daddr);
            __builtin_amdgcn_s_setprio(1);
            pacc[0] = __builtin_amdgcn_mfma_f32_16x16x32_bf16(dA, vf0, pacc[0], 0, 0, 0);
            pacc[1] = __builtin_amdgcn_mfma_f32_16x16x32_bf16(dA, vf1, pacc[1], 0, 0, 0);
            __builtin_amdgcn_s_setprio(0);
        }
        // prefetch V(t+1)
        vf0 = *(const s16x8*)(vp + jn);
        vf1 = *(const s16x8*)(vp + 16 * 4096 + jn);

        // ---- outer masked flash softmax ----
        {
            float ds = 0.f;
#pragma unroll
            for (int hh = 0; hh < 4; ++hh)
                ds += bf2f(*(const unsigned short*)(smem + DOTS + hh * 1280 + srow * 80 + scol * 2));
            float e = p1v + p2c; e = e > 0.f ? e : ALPHA_LR * e;
            float l = adjc > 0 ? e + ds : NEGV;
            float tm = wmax32(l);
            float Mn = fmaxf(Mrun, tm);
            float p = __expf(l - Mn);
            float ps = wsum32(p);
            float al = __expf(Mrun - Mn);
            Lrun = Lrun * al + ps;
            Mrun = Mn;
            if ((ln & 31) == 0) *(float*)(smem + ALP + srow * 4) = al;
            *(unsigned short*)(smem + PTIL + srow * 80 + scol * 2) = bf16_rne(p);
        }
        // prefetch adj/p2 (t+1)
        adjc = adj[(size_t)(i0 + srow) * NROWS + jn + scol];
        p2c  = p2g[jn + scol];
        __syncthreads();  // B2: ptil/alpha visible

        // ---- A@Wh with flash rescale ----
        {
            float alr[4];
#pragma unroll
            for (int r = 0; r < 4; ++r)
                alr[r] = *(const float*)(smem + ALP + (lhi * 4 + r) * 4);
#pragma unroll
            for (int nt = 0; nt < 2; ++nt)
#pragma unroll
                for (int r = 0; r < 4; ++r) wacc[nt][r] *= alr[r];
            s16x8 pA = *(const s16x8*)(smem + paddr);
            __builtin_amdgcn_s_setprio(1);
            wacc[0] = __builtin_amdgcn_mfma_f32_16x16x32_bf16(pA, wf0, wacc[0], 0, 0, 0);
            wacc[1] = __builtin_amdgcn_mfma_f32_16x16x32_bf16(pA, wf1, wacc[1], 0, 0, 0);
            __builtin_amdgcn_s_setprio(0);
        }
        // prefetch Wh(t+1)
        wf0 = *(const s16x8*)(wp + jn);
        wf1 = *(const s16x8*)(wp + 16 * 4096 + jn);
    }

    // ---- epilogue: per-chunk partials ----
    const size_t pbase = (size_t)(rt * 2 + ch) * 16 * 256;
#pragma unroll
    for (int nt = 0; nt < 2; ++nt)
#pragma unroll
        for (int r = 0; r < 4; ++r) {
            int row = lhi * 4 + r;
            int col = h * 64 + jg * 32 + nt * 16 + l15;
            pacc_o[pbase + row * 256 + col] = bf16_rne(pacc[nt][r]);
            wacc_o[pbase + row * 256 + col] = bf16_rne(wacc[nt][r]);
        }
    if ((ln & 31) == 0) {
        ml_o[((size_t)(rt * 2 + ch) * 16 + srow) * 2]     = Mrun;
        ml_o[((size_t)(rt * 2 + ch) * 16 + srow) * 2 + 1] = Lrun;
    }
}

// ---------------------------------------------------------------------------
// Merge: combine 2 j-chunks, Wh0 row softmax, elu, store.
// ---------------------------------------------------------------------------
__global__ __launch_bounds__(256) void merge_kernel(
    const unsigned short* __restrict__ pacc_b, const unsigned short* __restrict__ wacc_b,
    const float* __restrict__ ml, float* __restrict__ out)
{
    const int rt = blockIdx.x;
    const int tid = threadIdx.x;
    const int row = tid >> 4;
    const int cg = tid & 15;

    const size_t b0 = ((size_t)(rt * 2 + 0) * 16 + row) * 256 + cg * 16;
    const size_t b1 = ((size_t)(rt * 2 + 1) * 16 + row) * 256 + cg * 16;
    float M0 = ml[((size_t)(rt * 2 + 0) * 16 + row) * 2];
    float L0 = ml[((size_t)(rt * 2 + 0) * 16 + row) * 2 + 1];
    float M1 = ml[((size_t)(rt * 2 + 1) * 16 + row) * 2];
    float L1 = ml[((size_t)(rt * 2 + 1) * 16 + row) * 2 + 1];
    float M = fmaxf(M0, M1);
    float s0 = __expf(M0 - M), s1 = __expf(M1 - M);
    float invL = 1.0f / (L0 * s0 + L1 * s1);

    u16x8 pa[2][2], wa[2][2];
#pragma unroll
    for (int k = 0; k < 2; ++k) {
        pa[0][k] = *(const u16x8*)(pacc_b + b0 + k * 8);
        pa[1][k] = *(const u16x8*)(pacc_b + b1 + k * 8);
        wa[0][k] = *(const u16x8*)(wacc_b + b0 + k * 8);
        wa[1][k] = *(const u16x8*)(wacc_b + b1 + k * 8);
    }
    float p[16], wv[16];
    float mx = -3.0e38f;
#pragma unroll
    for (int k = 0; k < 16; ++k) {
        p[k] = bf2f(pa[0][k >> 3][k & 7]) + bf2f(pa[1][k >> 3][k & 7]);
        wv[k] = (bf2f(wa[0][k >> 3][k & 7]) * s0 + bf2f(wa[1][k >> 3][k & 7]) * s1) * invL;
        mx = fmaxf(mx, p[k]);
    }
    mx = wmax16(mx);
    float sm = 0.f;
#pragma unroll
    for (int k = 0; k < 16; ++k) { p[k] = __expf(p[k] - mx); sm += p[k]; }
    sm = wsum16(sm);
    float inv = 1.0f / sm;
    float* orow = out + ((size_t)(rt * 16 + row)) * 256 + cg * 16;
#pragma unroll
    for (int k4 = 0; k4 < 4; ++k4) {
        float4 o;
        float v;
        v = wv[k4*4+0] + p[k4*4+0] * inv; o.x = v > 0.f ? v : __expf(v) - 1.f;
        v = wv[k4*4+1] + p[k4*4+1] * inv; o.y = v > 0.f ? v : __expf(v) - 1.f;
        v = wv[k4*4+2] + p[k4*4+2] * inv; o.z = v > 0.f ? v : __expf(v) - 1.f;
        v = wv[k4*4+3] + p[k4*4+3] * inv; o.w = v > 0.f ? v : __expf(v) - 1.f;
        *(float4*)(orow + k4 * 4) = o;
    }
}

extern "C" void kernel_launch(void* const* d_in, const int* in_sizes, int n_in,
                              void* d_out, int out_size, void* d_ws, size_t ws_size,
                              hipStream_t stream)
{
    const float* h      = (const float*)d_in[0];
    const int*   adj    = (const int*)d_in[1];
    const float* W      = (const float*)d_in[2];
    const float* Wl_w   = (const float*)d_in[3];
    const float* Wl_b   = (const float*)d_in[4];
    const float* Wqkv_w = (const float*)d_in[5];
    const float* Wqkv_b = (const float*)d_in[6];
    const float* a      = (const float*)d_in[7];
    float* out = (float*)d_out;

    float* ws = (float*)d_ws;
    float* Whb = ws;                                        // 1M f32; pacc_b later
    unsigned short* u16b  = (unsigned short*)(ws + (1 << 20));
    unsigned short* qh    = u16b;                           // 1M u16 each
    unsigned short* kh    = u16b + (1 << 20);
    unsigned short* vth   = u16b + (2 << 20);
    unsigned short* wht   = u16b + (3 << 20);
    unsigned short* Whi   = u16b + (4 << 20);               // 131072
    unsigned short* Wlo   = Whi + 131072;
    unsigned short* Qhi   = Wlo + 131072;                   // 196608
    unsigned short* Qlo   = Qhi + 196608;
    unsigned short* WcThi = Qlo + 196608;                   // 131072
    unsigned short* WcTlo = WcThi + 131072;
    float* p1b    = ws + 3670016;
    float* p2b    = p1b + 4096;
    float* statsb = p2b + 4096;                             // 262144
    float* mlb    = statsb + 262144;                        // 16384
    unsigned short* pacc_b = (unsigned short*)Whb;          // 2M u16 (over Whb)
    unsigned short* wacc_b = (unsigned short*)(ws + 3960832); // 2M u16

    dim3 blk(256);
    // weight conversion
    wprep<<<dim3(768), blk, 0, stream>>>(W, Wqkv_w, Whi, Wlo, Qhi, Qlo);
    // WcT[n=256][k=512] = Wl_w @ W^T (bf16 hi/lo out)
    gemm_mfma<3, false><<<dim3(8, 4), blk, 0, stream>>>(
        Wl_w, Whi, Wlo, nullptr, nullptr, WcThi, WcTlo, nullptr, 256, 512, 256);
    // Wh = h @ WcT^T + Wl_b  (f32 + WhT bf16)
    gemm_mfma<1, true><<<dim3(4, 64), blk, 0, stream>>>(
        h, WcThi, WcTlo, Wl_b, Whb, wht, nullptr, nullptr, 4096, 256, 512);
    // qkv = Wh @ Wqkv_w^T + Wqkv_b  (q,k row bf16; vT bf16)
    gemm_mfma<2, true><<<dim3(12, 64), blk, 0, stream>>>(
        Whb, Qhi, Qlo, Wqkv_b, nullptr, qh, kh, vth, 4096, 768, 256);
    // p1, p2
    compute_p<<<dim3(256), blk, 0, stream>>>(Whb, a, p1b, p2b);
    // inner softmax stats
    stats_kernel<<<dim3(2048), blk, 0, stream>>>(qh, kh, statsb);
    // main fused sweep
    main_attn<<<dim3(512), dim3(512), 0, stream>>>(
        qh, kh, vth, wht, statsb, p1b, p2b, adj, pacc_b, wacc_b, mlb);
    // merge + epilogue
    merge_kernel<<<dim3(256), blk, 0, stream>>>(pacc_b, wacc_b, mlb, out);
}